// Round 5
// baseline (314.893 us; speedup 1.0000x reference)
//
#include <hip/hip_runtime.h>
#include <math.h>

#define DEVFN __device__ __forceinline__

typedef __bf16 bf16x8 __attribute__((ext_vector_type(8)));
typedef float f32x4 __attribute__((ext_vector_type(4)));

constexpr int T_ = 32;
constexpr int HW = 128;
constexpr int C1IN = 1928;        // cnn1 input channels
constexpr int C1 = 964;

DEVFN float sigm(float x) { return 1.0f / (1.0f + __expf(-x)); }

DEVFN ushort f2b(float v) {       // fp32 -> bf16 (RNE)
    union { float f; unsigned u; } x; x.f = v;
    unsigned r = x.u + 0x7fffu + ((x.u >> 16) & 1u);
    return (ushort)(r >> 16);
}

// ---------------------------------------------------------------------------
// conv_con (4x4 s2) + relu + maxpool 2x2 -> y[n][961]
__global__ void k_sca_conv(const float* __restrict__ replay, const float* __restrict__ wc,
                           const float* __restrict__ bc, float* __restrict__ y) {
    const int n = blockIdx.x;
    const int idx = blockIdx.y * 256 + threadIdx.x;
    if (idx >= 961) return;
    const float* x = replay + (size_t)n * 8 * HW * HW;     // channel 0
    float wr_[16];
    #pragma unroll
    for (int t = 0; t < 16; ++t) wr_[t] = wc[t];
    const float bcv = bc[0];
    const int i = idx / 31, j = idx % 31;
    float m = 0.0f;
    #pragma unroll
    for (int di = 0; di < 2; ++di)
    #pragma unroll
    for (int dj = 0; dj < 2; ++dj) {
        const int h0 = 2 * (2 * i + di), w0 = 2 * (2 * j + dj);
        float acc = bcv;
        #pragma unroll
        for (int p = 0; p < 4; ++p)
        #pragma unroll
        for (int q = 0; q < 4; ++q)
            acc += x[(h0 + p) * HW + (w0 + q)] * wr_[p * 4 + q];
        m = fmaxf(m, fmaxf(acc, 0.0f));
    }
    y[n * 961 + idx] = m;
}

// fc_con: sca[n][o] = y[n] . fcw[o] + fcb[o]   (one wave per output)
__global__ void k_sca_fc(const float* __restrict__ y, const float* __restrict__ fcw,
                         const float* __restrict__ fcb, float* __restrict__ sca) {
    const int n = blockIdx.x;
    const int wid = threadIdx.x >> 6, lane = threadIdx.x & 63;
    const int o = blockIdx.y * 4 + wid;                    // < 200
    float acc = 0.f;
    for (int m = lane; m < 961; m += 64)
        acc += y[n * 961 + m] * fcw[(size_t)o * 961 + m];
    #pragma unroll
    for (int off = 32; off > 0; off >>= 1) acc += __shfl_down(acc, off);
    if (lane == 0) sca[n * 200 + o] = acc + fcb[o];
}

// ---------------------------------------------------------------------------
__global__ void k_wsum(const float* __restrict__ w1, float* __restrict__ wsum) {
    const int oc = blockIdx.x;
    const float* wr = w1 + (size_t)oc * C1IN * 2;
    float s0 = 0.f, s1 = 0.f;
    for (int ic = threadIdx.x; ic < C1IN; ic += 64) {
        s0 += wr[ic * 2 + 0];
        s1 += wr[ic * 2 + 1];
    }
    #pragma unroll
    for (int off = 32; off > 0; off >>= 1) {
        s0 += __shfl_down(s0, off);
        s1 += __shfl_down(s1, off);
    }
    if (threadIdx.x == 0) { wsum[oc * 2] = s0; wsum[oc * 2 + 1] = s1; }
}

__global__ void k_sa(const float* __restrict__ replay, const float* __restrict__ w1,
                     float* __restrict__ sa) {
    const int n = blockIdx.y;
    const int oc = blockIdx.x * blockDim.x + threadIdx.x;
    if (oc >= C1) return;
    const int chs[5]    = {1, 3, 5, 6, 7};
    const int scales[5] = {4, 2, 5, 2, 1914};
    const int offs[5]   = {0, 4, 6, 11, 13};
    float s0 = 0.f, s1 = 0.f;
    #pragma unroll
    for (int k = 0; k < 5; ++k) {
        int v = (int)replay[((size_t)n * 8 + chs[k]) * HW * HW];
        if (v > scales[k]) v = 0;
        if (v >= 1 && v <= scales[k] - 1) {
            const int ic = 1 + offs[k] + v;
            s0 += w1[((size_t)oc * C1IN + ic) * 2 + 0];
            s1 += w1[((size_t)oc * C1IN + ic) * 2 + 1];
        }
    }
    sa[(n * C1 + oc) * 2 + 0] = s0;
    sa[(n * C1 + oc) * 2 + 1] = s1;
}

// ---------------------------------------------------------------------------
// cnn1 low-rank decomposition + relu + pool(1,2), writes Bt2 (transposed,
// bf16): Bt2[(n*100 + u)][oc] = p1[n][oc][u] for u<99; u=99 zero pad row.
// grid.y = 64 -> cols 0..1023 fully covered (oc>=964 zeros). Block (0,0)
// additionally zeros global pad row 6400.
template <int OCT>
__global__ void k_cnn1(const float* __restrict__ sca, const float* __restrict__ emb,
                       const float* __restrict__ w1, const float* __restrict__ b1,
                       const float* __restrict__ wsum, const float* __restrict__ sa,
                       ushort* __restrict__ Bt2) {
    const int n = blockIdx.x;
    const int ocBase = blockIdx.y * OCT;
    const int tx = threadIdx.x;
    __shared__ float ev[200], sv[200], dv[200];
    __shared__ float oscal[OCT][7];
    __shared__ float vals[OCT][100];
    for (int i = tx; i < 200; i += blockDim.x) {
        const float e0 = emb[i], e1 = emb[200 + i];
        ev[i] = e0;
        dv[i] = e1 - e0;
        sv[i] = sca[n * 200 + i] - e0;
    }
    for (int i = tx; i < OCT * 7; i += blockDim.x) {
        const int ocl = i / 7, f = i % 7;
        const int oc = ocBase + ocl;
        float v = 0.f;
        if (oc < C1) {
            switch (f) {
                case 0: v = wsum[oc * 2 + 0]; break;
                case 1: v = wsum[oc * 2 + 1]; break;
                case 2: v = b1[oc]; break;
                case 3: v = w1[(size_t)oc * C1IN * 2 + 0]; break;
                case 4: v = w1[(size_t)oc * C1IN * 2 + 1]; break;
                case 5: v = sa[(n * C1 + oc) * 2 + 0]; break;
                case 6: v = sa[(n * C1 + oc) * 2 + 1]; break;
            }
        }
        oscal[ocl][f] = v;
    }
    __syncthreads();
    for (int item = tx; item < OCT * 99; item += blockDim.x) {
        const int ocl = item / 99, u = item % 99;
        const int oc = ocBase + ocl;
        float res = 0.f;
        if (oc < C1) {
            const float ws0 = oscal[ocl][0], ws1 = oscal[ocl][1], bb = oscal[ocl][2];
            const float a0 = oscal[ocl][3], a1 = oscal[ocl][4];
            const float s0 = oscal[ocl][5], s1 = oscal[ocl][6];
            float r = -INFINITY;
            #pragma unroll
            for (int dw = 0; dw < 2; ++dw) {
                const int ww = 2 * u + dw;
                const float o = bb + ws0 * ev[ww] + ws1 * ev[ww + 1]
                                   + a0 * sv[ww] + a1 * sv[ww + 1]
                                   + s0 * dv[ww] + s1 * dv[ww + 1];
                r = fmaxf(r, o);
            }
            res = fmaxf(r, 0.0f);
        }
        vals[ocl][u] = res;
    }
    __syncthreads();
    // transposed write: OCT ocs x 100 rows
    for (int i = tx; i < OCT * 100; i += blockDim.x) {
        const int u = i >> 4, ocl = i & 15;
        const float v = (u < 99) ? vals[ocl][u] : 0.0f;
        Bt2[(size_t)(n * 100 + u) * 1024 + ocBase + ocl] = f2b(v);
    }
    if (n == 0 && ocBase == 0) {
        for (int i = tx; i < 1024; i += blockDim.x)
            Bt2[(size_t)6400 * 1024 + i] = 0;
    }
}

// ---------------------------------------------------------------------------
// weight prep: A2 panels [2][512][1024] from w2; A3 panels [2][256][512] from
// w3; whhT (permuted gate layout) from whh. Zero-padded.
__global__ void k_prep_w(const float* __restrict__ w2, const float* __restrict__ w3,
                         const float* __restrict__ whh,
                         ushort* __restrict__ A2, ushort* __restrict__ A3,
                         float* __restrict__ whhT) {
    const int idx = blockIdx.x * 256 + threadIdx.x;
    if (idx < 2 * 512 * 1024) {
        const int kw = idx >> 19;
        const int r = idx & 524287;
        const int oc = r >> 10, ic = r & 1023;
        const float v = (oc < 482 && ic < 964) ? w2[(size_t)oc * 1928 + ic * 2 + kw] : 0.f;
        A2[idx] = f2b(v);
    } else if (idx < 2 * 512 * 1024 + 2 * 256 * 512) {
        const int j = idx - 2 * 512 * 1024;
        const int kw = j >> 17;
        const int r = j & 131071;
        const int oc = r >> 9, ic = r & 511;
        const float v = (oc < 241 && ic < 482) ? w3[(size_t)oc * 964 + ic * 2 + kw] : 0.f;
        A3[j] = f2b(v);
    } else {
        const int j = idx - (2 * 512 * 1024 + 2 * 256 * 512);
        if (j < 40000) {
            const int m = j / 400, p = j - m * 400;
            const int go = (p & 3) * 100 + (p >> 2);
            whhT[m * 400 + p] = whh[go * 100 + m];
        }
    }
}

// ---------------------------------------------------------------------------
// Conv-GEMM (w-shift form): C[m][r] = sum_k A0[m][k]*Bt[r][k] + A1[m][k]*Bt[r+1][k]
// A panels [2][MPAD][KICP] bf16, Bt [64*NTILES + 1][KICP] bf16.
// 64x64 tile, 4 waves (2x2), XOR-swizzled LDS, double-buffered, 1 barrier per
// K-step. XCD swizzle: each XCD gets a contiguous N-range x ALL M-tiles so B
// is fetched once chip-wide and A+B fit per-XCD L2.
// Epilogue: pool(1,2)+bias+relu -> w-contiguous [n][OCREAL][WOUT/2] (bf16 or f32).
template <int OCREAL, int WR, int WOUT, int KICP, int MPAD, bool OUTBF, int MT, int NTILES>
__global__ __launch_bounds__(256, 3) void k_gemm_conv(
    const ushort* __restrict__ A, const ushort* __restrict__ Bt,
    const float* __restrict__ bias, void* __restrict__ outv) {
    constexpr int BK = 64;
    constexpr int NT = KICP / BK;
    constexpr int ASZ = 64 * 64;       // shorts per A-panel tile
    constexpr int BSZ = 65 * 64;
    constexpr int NWG = MT * NTILES;
    __shared__ __align__(16) ushort As0[2 * ASZ];
    __shared__ __align__(16) ushort As1[2 * ASZ];
    __shared__ __align__(16) ushort Bs[2 * BSZ];

    const int bid = blockIdx.x;
    const int sid = (bid & 7) * (NWG / 8) + (bid >> 3);
    const int mBase = (sid % MT) * 64;
    const int nBase = (sid / MT) * 64;

    const int tx = threadIdx.x;
    const int wave = tx >> 6, lane = tx & 63;
    const int wm = wave >> 1, wn = wave & 1;
    const int lr = lane & 15, lk = lane >> 4;
    const ushort* A1p = A + (size_t)MPAD * KICP;

    f32x4 acc[2][2] = {};
    uint4 ra0[2], ra1[2], rb[3];

    auto LOAD = [&](int kt) {
        const int k0 = kt * BK;
        #pragma unroll
        for (int p = 0; p < 2; ++p) {
            const int q = tx + p * 256, row = q >> 3, c = q & 7;
            ra0[p] = *(const uint4*)&A[(size_t)(mBase + row) * KICP + k0 + c * 8];
            ra1[p] = *(const uint4*)&A1p[(size_t)(mBase + row) * KICP + k0 + c * 8];
        }
        #pragma unroll
        for (int p = 0; p < 3; ++p) {
            const int q = tx + p * 256, row = q >> 3, c = q & 7;
            if (row < 65)
                rb[p] = *(const uint4*)&Bt[(size_t)(nBase + row) * KICP + k0 + c * 8];
        }
    };
    auto STORE = [&](int buf) {
        #pragma unroll
        for (int p = 0; p < 2; ++p) {
            const int q = tx + p * 256, row = q >> 3, c = q & 7;
            const int col = (c * 8) ^ ((row & 7) << 3);
            *(uint4*)&As0[buf * ASZ + row * 64 + col] = ra0[p];
            *(uint4*)&As1[buf * ASZ + row * 64 + col] = ra1[p];
        }
        #pragma unroll
        for (int p = 0; p < 3; ++p) {
            const int q = tx + p * 256, row = q >> 3, c = q & 7;
            if (row < 65) {
                const int col = (c * 8) ^ ((row & 7) << 3);
                *(uint4*)&Bs[buf * BSZ + row * 64 + col] = rb[p];
            }
        }
    };

    LOAD(0);
    STORE(0);
    if (NT > 1) LOAD(1);
    __syncthreads();

    for (int kt = 0; kt < NT; ++kt) {
        const int cur = kt & 1;
        #pragma unroll
        for (int ks = 0; ks < 2; ++ks) {
            bf16x8 a0[2], a1[2], b0[2], b1[2];
            #pragma unroll
            for (int i = 0; i < 2; ++i) {
                const int row = wm * 32 + i * 16 + lr;
                const int col = (ks * 32 + lk * 8) ^ ((row & 7) << 3);
                a0[i] = *(const bf16x8*)&As0[cur * ASZ + row * 64 + col];
                a1[i] = *(const bf16x8*)&As1[cur * ASZ + row * 64 + col];
            }
            #pragma unroll
            for (int j = 0; j < 2; ++j) {
                const int row = wn * 32 + j * 16 + lr;
                const int col = (ks * 32 + lk * 8) ^ ((row & 7) << 3);
                b0[j] = *(const bf16x8*)&Bs[cur * BSZ + row * 64 + col];
                const int row1 = row + 1;
                const int col1 = (ks * 32 + lk * 8) ^ ((row1 & 7) << 3);
                b1[j] = *(const bf16x8*)&Bs[cur * BSZ + row1 * 64 + col1];
            }
            #pragma unroll
            for (int i = 0; i < 2; ++i)
                #pragma unroll
                for (int j = 0; j < 2; ++j) {
                    acc[i][j] = __builtin_amdgcn_mfma_f32_16x16x32_bf16(a0[i], b0[j], acc[i][j], 0, 0, 0);
                    acc[i][j] = __builtin_amdgcn_mfma_f32_16x16x32_bf16(a1[i], b1[j], acc[i][j], 0, 0, 0);
                }
        }
        if (kt + 1 < NT) {
            STORE(cur ^ 1);
            if (kt + 2 < NT) LOAD(kt + 2);
        }
        __syncthreads();
    }

    ushort* outb = (ushort*)outv;
    float*  outf = (float*)outv;
    constexpr int UOUT = WOUT / 2;
    #pragma unroll
    for (int i = 0; i < 2; ++i) {
        const int m0 = mBase + wm * 32 + i * 16 + lk * 4;
        #pragma unroll
        for (int j = 0; j < 2; ++j) {
            const int r = nBase + wn * 32 + j * 16 + lr;
            const int n = r / WR, w = r - n * WR;
            #pragma unroll
            for (int reg = 0; reg < 4; ++reg) {
                const float v = acc[i][j][reg];
                const float vo = __shfl_xor(v, 1);
                const int m = m0 + reg;
                if (((lr & 1) == 0) && (w < WOUT) && (m < OCREAL)) {
                    const float val = fmaxf(fmaxf(v, vo) + bias[m], 0.0f);
                    const size_t oi = ((size_t)n * OCREAL + m) * UOUT + (w >> 1);
                    if (OUTBF) outb[oi] = f2b(val);
                    else       outf[oi] = val;
                }
            }
        }
    }
}

// ---------------------------------------------------------------------------
// transpose p2b [n][482][49] bf16 -> Bt3 [(n*50+u)][512] bf16 (u=49 row and
// oc>=482 cols zero). Block n=0 also zeros global pad row 3200.
__global__ __launch_bounds__(256) void k_tr3(const ushort* __restrict__ p2b,
                                             ushort* __restrict__ Bt3) {
    const int n = blockIdx.x;           // 64
    __shared__ ushort s[23618];         // 482*49
    const int tx = threadIdx.x;
    for (int i = tx; i < 23618; i += 256) s[i] = p2b[(size_t)n * 23618 + i];
    __syncthreads();
    for (int j = tx; j < 50 * 512; j += 256) {
        const int u = j >> 9, oc = j & 511;
        const ushort v = (u < 49 && oc < 482) ? s[oc * 49 + u] : (ushort)0;
        Bt3[(size_t)(n * 50 + u) * 512 + oc] = v;
    }
    if (n == 0) {
        for (int i = tx; i < 512; i += 256) Bt3[(size_t)3200 * 512 + i] = 0;
    }
}

// ---------------------------------------------------------------------------
// cnn4 (fp32, small): in [N][IC][WIN], w [OC][IC][2], out [N][OC][WIN-1]
template <int IC, int OC, int WIN>
__global__ __launch_bounds__(256) void k_conv(const float* __restrict__ in,
                                              const float* __restrict__ w,
                                              const float* __restrict__ bias,
                                              float* __restrict__ out) {
    constexpr int NOUT = WIN - 1;
    constexpr int OCT = 32;
    constexpr int KT = 32;
    constexpr int MAXU = (NOUT + 15) / 16;
    constexpr int PSTRIDE = (WIN % 2) ? (WIN + 1) : WIN;
    constexpr int WSTRIDE = 2 * KT + 2;

    __shared__ __align__(16) float pt[KT * PSTRIDE];
    __shared__ __align__(16) float wt[OCT * WSTRIDE];

    const int n = blockIdx.x;
    const int ocBase = blockIdx.y * OCT;
    const int tx = threadIdx.x;
    const int ocg = tx >> 4;
    const int ol = tx & 15;
    const int oc0 = ocBase + 2 * ocg;
    const int oc1 = oc0 + 1;

    float acc[2][MAXU];
    #pragma unroll
    for (int a = 0; a < 2; ++a)
        #pragma unroll
        for (int r = 0; r < MAXU; ++r) acc[a][r] = 0.f;

    const float* inn = in + (size_t)n * IC * WIN;

    for (int icb = 0; icb < IC; icb += KT) {
        const int kt = min(KT, IC - icb);
        __syncthreads();
        for (int i = tx; i < KT * WIN; i += 256) {
            const int r = i / WIN, c = i - r * WIN;
            pt[r * PSTRIDE + c] = (r < kt) ? inn[icb * WIN + i] : 0.0f;
        }
        for (int i = tx; i < OCT * 2 * KT; i += 256) {
            const int r = i / (2 * KT), c = i - r * (2 * KT);
            const int oc = ocBase + r;
            const int ic = icb + (c >> 1);
            float v = 0.f;
            if (oc < OC && ic < IC) v = w[((size_t)oc * IC + ic) * 2 + (c & 1)];
            wt[r * WSTRIDE + c] = v;
        }
        __syncthreads();
        #pragma unroll 4
        for (int ic = 0; ic < KT; ++ic) {
            const float2 w0 = *(const float2*)&wt[(2 * ocg) * WSTRIDE + 2 * ic];
            const float2 w1v = *(const float2*)&wt[(2 * ocg + 1) * WSTRIDE + 2 * ic];
            #pragma unroll
            for (int r = 0; r < MAXU; ++r) {
                const int u = ol + 16 * r;
                if (u < NOUT) {
                    const float p0 = pt[ic * PSTRIDE + u];
                    const float p1v = pt[ic * PSTRIDE + u + 1];
                    acc[0][r] += w0.x * p0 + w0.y * p1v;
                    acc[1][r] += w1v.x * p0 + w1v.y * p1v;
                }
            }
        }
    }

    const float b0 = (oc0 < OC) ? bias[oc0] : 0.f;
    const float b1v = (oc1 < OC) ? bias[oc1] : 0.f;
    float* outn = out + (size_t)n * OC * NOUT;
    #pragma unroll
    for (int r = 0; r < MAXU; ++r) {
        const int u = ol + 16 * r;
        if (u < NOUT) {
            if (oc0 < OC) outn[oc0 * NOUT + u] = fmaxf(acc[0][r] + b0, 0.f);
            if (oc1 < OC) outn[oc1 * NOUT + u] = fmaxf(acc[1][r] + b1v, 0.f);
        }
    }
}

// ---------------------------------------------------------------------------
// fc_cnn: seq[n][o] = z4[n][2300] . W[o] + b[o]   (one wave per output)
__global__ void k_fc_cnn(const float* __restrict__ z4, const float* __restrict__ w,
                         const float* __restrict__ b, float* __restrict__ seq) {
    const int n = blockIdx.x;
    const int wid = threadIdx.x >> 6, lane = threadIdx.x & 63;
    const int o = blockIdx.y * 4 + wid;                    // < 100
    const float4* zr = (const float4*)(z4 + (size_t)n * 2300);
    const float4* wr = (const float4*)(w + (size_t)o * 2300);
    float acc = 0.f;
    for (int m = lane; m < 575; m += 64) {
        const float4 wv = wr[m];
        const float4 zv = zr[m];
        acc += wv.x * zv.x + wv.y * zv.y + wv.z * zv.z + wv.w * zv.w;
    }
    #pragma unroll
    for (int off = 32; off > 0; off >>= 1) acc += __shfl_down(acc, off);
    if (lane == 0) seq[n * 100 + o] = acc + b[o];
}

// xg (PERMUTED gate layout p: gate=(p%4), unit=p/4) = seq @ W_ih.T + b_ih + b_hh
__global__ void k_xg(const float* __restrict__ seq, const float* __restrict__ wih,
                     const float* __restrict__ bih, const float* __restrict__ bhh,
                     float* __restrict__ xg) {
    const int n = blockIdx.x;
    __shared__ __align__(16) float s[100];
    if (threadIdx.x < 100) s[threadIdx.x] = seq[n * 100 + threadIdx.x];
    __syncthreads();
    const int p = threadIdx.x;
    if (p < 400) {
        const int go = (p & 3) * 100 + (p >> 2);
        const float4* wr = (const float4*)(wih + (size_t)go * 100);
        const float4* s4 = (const float4*)s;
        float4 a = {0.f, 0.f, 0.f, 0.f};
        #pragma unroll
        for (int m = 0; m < 25; ++m) {
            const float4 wv = wr[m];
            const float4 sv = s4[m];
            a.x += wv.x * sv.x; a.y += wv.y * sv.y;
            a.z += wv.z * sv.z; a.w += wv.w * sv.w;
        }
        xg[n * 400 + p] = bih[go] + bhh[go] + a.x + a.y + a.z + a.w;
    }
}

// LSTM: one block per batch; gate quadruple within a lane-quad -> 1 barrier/step
__global__ __launch_bounds__(512) void k_lstm(const float* __restrict__ xg,
                                              const float* __restrict__ whhT,
                                              const float* __restrict__ fw,
                                              const float* __restrict__ fb,
                                              float* __restrict__ outp) {
    const int bb = blockIdx.x;
    const int tx = threadIdx.x;
    __shared__ __align__(16) float hb[2][104];
    float wreg[100];
    if (tx < 400) {
        #pragma unroll
        for (int m = 0; m < 100; ++m) wreg[m] = whhT[m * 400 + tx];
    }
    float creg = 0.f;
    if (tx < 104) { hb[0][tx] = 0.f; hb[1][tx] = 0.f; }
    float xnext = (tx < 400) ? xg[(size_t)(bb * T_) * 400 + tx] : 0.f;
    __syncthreads();
    const int lane = tx & 63, base = lane & ~3;
    for (int t = 0; t < T_; ++t) {
        float acc = 0.f;
        if (tx < 400) {
            acc = xnext;
            if (t + 1 < T_) xnext = xg[(size_t)(bb * T_ + t + 1) * 400 + tx];
            const float4* h4 = (const float4*)&hb[t & 1][0];
            #pragma unroll
            for (int m4 = 0; m4 < 25; ++m4) {
                const float4 hv = h4[m4];
                acc += hv.x * wreg[4 * m4 + 0] + hv.y * wreg[4 * m4 + 1]
                     + hv.z * wreg[4 * m4 + 2] + hv.w * wreg[4 * m4 + 3];
            }
        }
        const float gI = __shfl(acc, base + 0);
        const float gF = __shfl(acc, base + 1);
        const float gG = __shfl(acc, base + 2);
        const float gO = __shfl(acc, base + 3);
        if (tx < 400) {
            const float cn = sigm(gF) * creg + sigm(gI) * tanhf(gG);
            creg = cn;
            if ((tx & 3) == 0) hb[(t + 1) & 1][tx >> 2] = sigm(gO) * tanhf(cn);
        }
        __syncthreads();
    }
    if (tx < 2) {
        float acc = fb[tx];
        for (int j = 0; j < 100; ++j) acc += hb[0][j] * fw[tx * 100 + j];
        outp[bb * 2 + tx] = acc;
    }
}

// ---------------------------------------------------------------------------
extern "C" void kernel_launch(void* const* d_in, const int* in_sizes, int n_in,
                              void* d_out, int out_size, void* d_ws, size_t ws_size,
                              hipStream_t stream) {
    (void)in_sizes; (void)n_in; (void)out_size; (void)ws_size;
    const float* replay = (const float*)d_in[0];
    const float* emb    = (const float*)d_in[1];
    const float* ccw    = (const float*)d_in[2];
    const float* ccb    = (const float*)d_in[3];
    const float* fcw    = (const float*)d_in[4];
    const float* fcb    = (const float*)d_in[5];
    const float* w1     = (const float*)d_in[6];
    const float* b1     = (const float*)d_in[7];
    const float* w2     = (const float*)d_in[8];
    const float* b2     = (const float*)d_in[9];
    const float* w3     = (const float*)d_in[10];
    const float* b3     = (const float*)d_in[11];
    const float* w4     = (const float*)d_in[12];
    const float* b4     = (const float*)d_in[13];
    const float* fcnw   = (const float*)d_in[14];
    const float* fcnb   = (const float*)d_in[15];
    const float* wih    = (const float*)d_in[16];
    const float* whh    = (const float*)d_in[17];
    const float* bih    = (const float*)d_in[18];
    const float* bhh    = (const float*)d_in[19];
    const float* fow    = (const float*)d_in[20];
    const float* fob    = (const float*)d_in[21];

    float* ws = (float*)d_ws;
    float*  sca  = ws + 0;                      // 12800
    float*  wsum = ws + 12800;                  // 2048
    float*  sa   = ws + 14848;                  // 123392 -> 138240
    float*  seq  = ws + 138240;                 // 6400
    float*  xg   = ws + 144640;                 // 25600
    float*  whhT = ws + 170240;                 // 40000 -> 210240
    float*  yb   = ws + 210240;                 // 61504 -> pad 272384
    float*  p3   = ws + 272384;                 // 370176 -> 642560
    float*  z4   = ws + 642560;                 // 147200 -> 789760
    ushort* A2   = (ushort*)(ws + 789760);      // 2*512*1024 sh = 524288 fl
    ushort* A3   = (ushort*)(ws + 1314048);     // 2*256*512 sh = 131072 fl
    ushort* Bt2  = (ushort*)(ws + 1445120);     // 6401*1024 sh = 3277312 fl
    ushort* Bt3  = (ushort*)(ws + 4722432);     // 3201*512 sh = 819456 fl
    ushort* p2b  = (ushort*)(ws + 5541888);     // 64*482*49 sh = 755776 fl (end 6297664)
    float*  outp = (float*)d_out;

    k_sca_conv<<<dim3(64, 4), 256, 0, stream>>>(replay, ccw, ccb, yb);
    k_sca_fc<<<dim3(64, 50), 256, 0, stream>>>(yb, fcw, fcb, sca);
    k_wsum<<<964, 64, 0, stream>>>(w1, wsum);
    k_sa<<<dim3(4, 64), 256, 0, stream>>>(replay, w1, sa);
    k_prep_w<<<5277, 256, 0, stream>>>(w2, w3, whh, A2, A3, whhT);
    k_cnn1<16><<<dim3(64, 64), 256, 0, stream>>>(sca, emb, w1, b1, wsum, sa, Bt2);
    // gemm1: M=512(482), K=1024(964), B rows 64*100; out -> p2b bf16 [n][482][49]
    k_gemm_conv<482, 100, 98, 1024, 512, true, 8, 100>
        <<<800, 256, 0, stream>>>(A2, Bt2, b2, p2b);
    k_tr3<<<64, 256, 0, stream>>>(p2b, Bt3);
    // gemm2: M=256(241), K=512(482), B rows 64*50; out -> p3 fp32 [n][241][24]
    k_gemm_conv<241, 50, 48, 512, 256, false, 4, 50>
        <<<200, 256, 0, stream>>>(A3, Bt3, b3, p3);
    k_conv<241, 100, 24><<<dim3(64, 4), 256, 0, stream>>>(p3, w4, b4, z4);
    k_fc_cnn<<<dim3(64, 25), 256, 0, stream>>>(z4, fcnw, fcnb, seq);
    k_xg<<<64, 512, 0, stream>>>(seq, wih, bih, bhh, xg);
    k_lstm<<<2, 512, 0, stream>>>(xg, whhT, fow, fob, outp);
}

// Round 6
// 287.672 us; speedup vs baseline: 1.0946x; 1.0946x over previous
//
#include <hip/hip_runtime.h>
#include <math.h>

#define DEVFN __device__ __forceinline__

typedef __bf16 bf16x8 __attribute__((ext_vector_type(8)));
typedef float f32x4 __attribute__((ext_vector_type(4)));

constexpr int T_ = 32;
constexpr int HW = 128;
constexpr int C1IN = 1928;        // cnn1 input channels
constexpr int C1 = 964;

DEVFN float sigm(float x) { return 1.0f / (1.0f + __expf(-x)); }

DEVFN ushort f2b(float v) {       // fp32 -> bf16 (RNE)
    union { float f; unsigned u; } x; x.f = v;
    unsigned r = x.u + 0x7fffu + ((x.u >> 16) & 1u);
    return (ushort)(r >> 16);
}

// ---------------------------------------------------------------------------
// conv_con (4x4 s2) + relu + maxpool 2x2 -> y[n][961]
__global__ void k_sca_conv(const float* __restrict__ replay, const float* __restrict__ wc,
                           const float* __restrict__ bc, float* __restrict__ y) {
    const int n = blockIdx.x;
    const int idx = blockIdx.y * 256 + threadIdx.x;
    if (idx >= 961) return;
    const float* x = replay + (size_t)n * 8 * HW * HW;     // channel 0
    float wr_[16];
    #pragma unroll
    for (int t = 0; t < 16; ++t) wr_[t] = wc[t];
    const float bcv = bc[0];
    const int i = idx / 31, j = idx % 31;
    float m = 0.0f;
    #pragma unroll
    for (int di = 0; di < 2; ++di)
    #pragma unroll
    for (int dj = 0; dj < 2; ++dj) {
        const int h0 = 2 * (2 * i + di), w0 = 2 * (2 * j + dj);
        float acc = bcv;
        #pragma unroll
        for (int p = 0; p < 4; ++p)
        #pragma unroll
        for (int q = 0; q < 4; ++q)
            acc += x[(h0 + p) * HW + (w0 + q)] * wr_[p * 4 + q];
        m = fmaxf(m, fmaxf(acc, 0.0f));
    }
    y[n * 961 + idx] = m;
}

// fc_con: sca[n][o] = y[n] . fcw[o] + fcb[o]   (one wave per output)
__global__ void k_sca_fc(const float* __restrict__ y, const float* __restrict__ fcw,
                         const float* __restrict__ fcb, float* __restrict__ sca) {
    const int n = blockIdx.x;
    const int wid = threadIdx.x >> 6, lane = threadIdx.x & 63;
    const int o = blockIdx.y * 4 + wid;                    // < 200
    float acc = 0.f;
    for (int m = lane; m < 961; m += 64)
        acc += y[n * 961 + m] * fcw[(size_t)o * 961 + m];
    #pragma unroll
    for (int off = 32; off > 0; off >>= 1) acc += __shfl_down(acc, off);
    if (lane == 0) sca[n * 200 + o] = acc + fcb[o];
}

// ---------------------------------------------------------------------------
__global__ void k_wsum(const float* __restrict__ w1, float* __restrict__ wsum) {
    const int oc = blockIdx.x;
    const float* wr = w1 + (size_t)oc * C1IN * 2;
    float s0 = 0.f, s1 = 0.f;
    for (int ic = threadIdx.x; ic < C1IN; ic += 64) {
        s0 += wr[ic * 2 + 0];
        s1 += wr[ic * 2 + 1];
    }
    #pragma unroll
    for (int off = 32; off > 0; off >>= 1) {
        s0 += __shfl_down(s0, off);
        s1 += __shfl_down(s1, off);
    }
    if (threadIdx.x == 0) { wsum[oc * 2] = s0; wsum[oc * 2 + 1] = s1; }
}

__global__ void k_sa(const float* __restrict__ replay, const float* __restrict__ w1,
                     float* __restrict__ sa) {
    const int n = blockIdx.y;
    const int oc = blockIdx.x * blockDim.x + threadIdx.x;
    if (oc >= C1) return;
    const int chs[5]    = {1, 3, 5, 6, 7};
    const int scales[5] = {4, 2, 5, 2, 1914};
    const int offs[5]   = {0, 4, 6, 11, 13};
    float s0 = 0.f, s1 = 0.f;
    #pragma unroll
    for (int k = 0; k < 5; ++k) {
        int v = (int)replay[((size_t)n * 8 + chs[k]) * HW * HW];
        if (v > scales[k]) v = 0;
        if (v >= 1 && v <= scales[k] - 1) {
            const int ic = 1 + offs[k] + v;
            s0 += w1[((size_t)oc * C1IN + ic) * 2 + 0];
            s1 += w1[((size_t)oc * C1IN + ic) * 2 + 1];
        }
    }
    sa[(n * C1 + oc) * 2 + 0] = s0;
    sa[(n * C1 + oc) * 2 + 1] = s1;
}

// ---------------------------------------------------------------------------
// cnn1 low-rank decomposition + relu + pool(1,2), writes Bt2 (transposed,
// bf16): Bt2[(n*100 + u)][oc] = p1[n][oc][u] for u<99; u=99 zero pad row.
// grid.y = 64 -> cols 0..1023 fully covered (oc>=964 zeros). Block (0,0)
// additionally zeros global pad row 6400.
template <int OCT>
__global__ void k_cnn1(const float* __restrict__ sca, const float* __restrict__ emb,
                       const float* __restrict__ w1, const float* __restrict__ b1,
                       const float* __restrict__ wsum, const float* __restrict__ sa,
                       ushort* __restrict__ Bt2) {
    const int n = blockIdx.x;
    const int ocBase = blockIdx.y * OCT;
    const int tx = threadIdx.x;
    __shared__ float ev[200], sv[200], dv[200];
    __shared__ float oscal[OCT][7];
    __shared__ float vals[OCT][100];
    for (int i = tx; i < 200; i += blockDim.x) {
        const float e0 = emb[i], e1 = emb[200 + i];
        ev[i] = e0;
        dv[i] = e1 - e0;
        sv[i] = sca[n * 200 + i] - e0;
    }
    for (int i = tx; i < OCT * 7; i += blockDim.x) {
        const int ocl = i / 7, f = i % 7;
        const int oc = ocBase + ocl;
        float v = 0.f;
        if (oc < C1) {
            switch (f) {
                case 0: v = wsum[oc * 2 + 0]; break;
                case 1: v = wsum[oc * 2 + 1]; break;
                case 2: v = b1[oc]; break;
                case 3: v = w1[(size_t)oc * C1IN * 2 + 0]; break;
                case 4: v = w1[(size_t)oc * C1IN * 2 + 1]; break;
                case 5: v = sa[(n * C1 + oc) * 2 + 0]; break;
                case 6: v = sa[(n * C1 + oc) * 2 + 1]; break;
            }
        }
        oscal[ocl][f] = v;
    }
    __syncthreads();
    for (int item = tx; item < OCT * 99; item += blockDim.x) {
        const int ocl = item / 99, u = item % 99;
        const int oc = ocBase + ocl;
        float res = 0.f;
        if (oc < C1) {
            const float ws0 = oscal[ocl][0], ws1 = oscal[ocl][1], bb = oscal[ocl][2];
            const float a0 = oscal[ocl][3], a1 = oscal[ocl][4];
            const float s0 = oscal[ocl][5], s1 = oscal[ocl][6];
            float r = -INFINITY;
            #pragma unroll
            for (int dw = 0; dw < 2; ++dw) {
                const int ww = 2 * u + dw;
                const float o = bb + ws0 * ev[ww] + ws1 * ev[ww + 1]
                                   + a0 * sv[ww] + a1 * sv[ww + 1]
                                   + s0 * dv[ww] + s1 * dv[ww + 1];
                r = fmaxf(r, o);
            }
            res = fmaxf(r, 0.0f);
        }
        vals[ocl][u] = res;
    }
    __syncthreads();
    // transposed write: OCT ocs x 100 rows
    for (int i = tx; i < OCT * 100; i += blockDim.x) {
        const int u = i >> 4, ocl = i & 15;
        const float v = (u < 99) ? vals[ocl][u] : 0.0f;
        Bt2[(size_t)(n * 100 + u) * 1024 + ocBase + ocl] = f2b(v);
    }
    if (n == 0 && ocBase == 0) {
        for (int i = tx; i < 1024; i += blockDim.x)
            Bt2[(size_t)6400 * 1024 + i] = 0;
    }
}

// ---------------------------------------------------------------------------
// weight prep: A2 panels [2][512][1024] from w2; A3 panels [2][256][512] from
// w3; whhT (permuted gate layout) from whh. Zero-padded.
__global__ void k_prep_w(const float* __restrict__ w2, const float* __restrict__ w3,
                         const float* __restrict__ whh,
                         ushort* __restrict__ A2, ushort* __restrict__ A3,
                         float* __restrict__ whhT) {
    const int idx = blockIdx.x * 256 + threadIdx.x;
    if (idx < 2 * 512 * 1024) {
        const int kw = idx >> 19;
        const int r = idx & 524287;
        const int oc = r >> 10, ic = r & 1023;
        const float v = (oc < 482 && ic < 964) ? w2[(size_t)oc * 1928 + ic * 2 + kw] : 0.f;
        A2[idx] = f2b(v);
    } else if (idx < 2 * 512 * 1024 + 2 * 256 * 512) {
        const int j = idx - 2 * 512 * 1024;
        const int kw = j >> 17;
        const int r = j & 131071;
        const int oc = r >> 9, ic = r & 511;
        const float v = (oc < 241 && ic < 482) ? w3[(size_t)oc * 964 + ic * 2 + kw] : 0.f;
        A3[j] = f2b(v);
    } else {
        const int j = idx - (2 * 512 * 1024 + 2 * 256 * 512);
        if (j < 40000) {
            const int m = j / 400, p = j - m * 400;
            const int go = (p & 3) * 100 + (p >> 2);
            whhT[m * 400 + p] = whh[go * 100 + m];
        }
    }
}

// ---------------------------------------------------------------------------
// Conv-GEMM (w-shift form): C[m][r] = sum_k A0[m][k]*Bt[r][k] + A1[m][k]*Bt[r+1][k]
// A panels [2][MPAD][KICP] bf16, Bt [64*NTILES + 1][KICP] bf16.
// 64x64 tile, 4 waves (2x2), XOR-swizzled LDS, double-buffered, 1 barrier per
// K-step. XCD swizzle: each XCD gets a contiguous N-range x ALL M-tiles.
// ALL prefetch registers are unconditionally defined (no guarded array
// elements -> no scratch demotion; round-5 lesson: guarded rb[3] caused
// ~250 MB of scratch-eviction HBM writes). The one extra B row (row 64,
// needed by the w-shift b1 fragment) is loaded redundantly by every thread
// into a plain uint4 and stored to LDS by tx<8 only.
// Epilogue: pool(1,2)+bias+relu -> w-contiguous [n][OCREAL][WOUT/2] (bf16 or f32).
template <int OCREAL, int WR, int WOUT, int KICP, int MPAD, bool OUTBF, int MT, int NTILES>
__global__ __launch_bounds__(256, 3) void k_gemm_conv(
    const ushort* __restrict__ A, const ushort* __restrict__ Bt,
    const float* __restrict__ bias, void* __restrict__ outv) {
    constexpr int BK = 64;
    constexpr int NT = KICP / BK;
    constexpr int ASZ = 64 * 64;       // shorts per A-panel tile
    constexpr int BSZ = 65 * 64;
    constexpr int NWG = MT * NTILES;
    __shared__ __align__(16) ushort As0[2 * ASZ];
    __shared__ __align__(16) ushort As1[2 * ASZ];
    __shared__ __align__(16) ushort Bs[2 * BSZ];

    const int bid = blockIdx.x;
    const int sid = (bid & 7) * (NWG / 8) + (bid >> 3);
    const int mBase = (sid % MT) * 64;
    const int nBase = (sid / MT) * 64;

    const int tx = threadIdx.x;
    const int wave = tx >> 6, lane = tx & 63;
    const int wm = wave >> 1, wn = wave & 1;
    const int lr = lane & 15, lk = lane >> 4;
    const ushort* A1p = A + (size_t)MPAD * KICP;

    f32x4 acc[2][2] = {};
    uint4 ra0[2], ra1[2], rb[2], rbx;

    auto LOAD = [&](int kt) {
        const int k0 = kt * BK;
        #pragma unroll
        for (int p = 0; p < 2; ++p) {
            const int q = tx + p * 256, row = q >> 3, c = q & 7;
            ra0[p] = *(const uint4*)&A[(size_t)(mBase + row) * KICP + k0 + c * 8];
            ra1[p] = *(const uint4*)&A1p[(size_t)(mBase + row) * KICP + k0 + c * 8];
            rb[p]  = *(const uint4*)&Bt[(size_t)(nBase + row) * KICP + k0 + c * 8];
        }
        // row 64 (first row of next n-tile): loaded by ALL threads (redundant,
        // unconditional) so no register is conditionally defined.
        rbx = *(const uint4*)&Bt[(size_t)(nBase + 64) * KICP + k0 + (tx & 7) * 8];
    };
    auto STORE = [&](int buf) {
        #pragma unroll
        for (int p = 0; p < 2; ++p) {
            const int q = tx + p * 256, row = q >> 3, c = q & 7;
            const int col = (c * 8) ^ ((row & 7) << 3);
            *(uint4*)&As0[buf * ASZ + row * 64 + col] = ra0[p];
            *(uint4*)&As1[buf * ASZ + row * 64 + col] = ra1[p];
            *(uint4*)&Bs[buf * BSZ + row * 64 + col] = rb[p];
        }
        if (tx < 8) {
            // row 64: (64&7)==0 -> swizzle is identity
            *(uint4*)&Bs[buf * BSZ + 64 * 64 + tx * 8] = rbx;
        }
    };

    LOAD(0);
    STORE(0);
    if (NT > 1) LOAD(1);
    __syncthreads();

    for (int kt = 0; kt < NT; ++kt) {
        const int cur = kt & 1;
        #pragma unroll
        for (int ks = 0; ks < 2; ++ks) {
            bf16x8 a0[2], a1[2], b0[2], b1[2];
            #pragma unroll
            for (int i = 0; i < 2; ++i) {
                const int row = wm * 32 + i * 16 + lr;
                const int col = (ks * 32 + lk * 8) ^ ((row & 7) << 3);
                a0[i] = *(const bf16x8*)&As0[cur * ASZ + row * 64 + col];
                a1[i] = *(const bf16x8*)&As1[cur * ASZ + row * 64 + col];
            }
            #pragma unroll
            for (int j = 0; j < 2; ++j) {
                const int row = wn * 32 + j * 16 + lr;
                const int col = (ks * 32 + lk * 8) ^ ((row & 7) << 3);
                b0[j] = *(const bf16x8*)&Bs[cur * BSZ + row * 64 + col];
                const int row1 = row + 1;
                const int col1 = (ks * 32 + lk * 8) ^ ((row1 & 7) << 3);
                b1[j] = *(const bf16x8*)&Bs[cur * BSZ + row1 * 64 + col1];
            }
            #pragma unroll
            for (int i = 0; i < 2; ++i)
                #pragma unroll
                for (int j = 0; j < 2; ++j) {
                    acc[i][j] = __builtin_amdgcn_mfma_f32_16x16x32_bf16(a0[i], b0[j], acc[i][j], 0, 0, 0);
                    acc[i][j] = __builtin_amdgcn_mfma_f32_16x16x32_bf16(a1[i], b1[j], acc[i][j], 0, 0, 0);
                }
        }
        if (kt + 1 < NT) {
            STORE(cur ^ 1);
            if (kt + 2 < NT) LOAD(kt + 2);
        }
        __syncthreads();
    }

    ushort* outb = (ushort*)outv;
    float*  outf = (float*)outv;
    constexpr int UOUT = WOUT / 2;
    #pragma unroll
    for (int i = 0; i < 2; ++i) {
        const int m0 = mBase + wm * 32 + i * 16 + lk * 4;
        #pragma unroll
        for (int j = 0; j < 2; ++j) {
            const int r = nBase + wn * 32 + j * 16 + lr;
            const int n = r / WR, w = r - n * WR;
            #pragma unroll
            for (int reg = 0; reg < 4; ++reg) {
                const float v = acc[i][j][reg];
                const float vo = __shfl_xor(v, 1);
                const int m = m0 + reg;
                if (((lr & 1) == 0) && (w < WOUT) && (m < OCREAL)) {
                    const float val = fmaxf(fmaxf(v, vo) + bias[m], 0.0f);
                    const size_t oi = ((size_t)n * OCREAL + m) * UOUT + (w >> 1);
                    if (OUTBF) outb[oi] = f2b(val);
                    else       outf[oi] = val;
                }
            }
        }
    }
}

// ---------------------------------------------------------------------------
// transpose p2b [n][482][49] bf16 -> Bt3 [(n*50+u)][512] bf16 (u=49 row and
// oc>=482 cols zero). Block n=0 also zeros global pad row 3200.
__global__ __launch_bounds__(256) void k_tr3(const ushort* __restrict__ p2b,
                                             ushort* __restrict__ Bt3) {
    const int n = blockIdx.x;           // 64
    __shared__ ushort s[23618];         // 482*49
    const int tx = threadIdx.x;
    for (int i = tx; i < 23618; i += 256) s[i] = p2b[(size_t)n * 23618 + i];
    __syncthreads();
    for (int j = tx; j < 50 * 512; j += 256) {
        const int u = j >> 9, oc = j & 511;
        const ushort v = (u < 49 && oc < 482) ? s[oc * 49 + u] : (ushort)0;
        Bt3[(size_t)(n * 50 + u) * 512 + oc] = v;
    }
    if (n == 0) {
        for (int i = tx; i < 512; i += 256) Bt3[(size_t)3200 * 512 + i] = 0;
    }
}

// ---------------------------------------------------------------------------
// cnn4 (fp32, small): in [N][IC][WIN], w [OC][IC][2], out [N][OC][WIN-1]
template <int IC, int OC, int WIN>
__global__ __launch_bounds__(256) void k_conv(const float* __restrict__ in,
                                              const float* __restrict__ w,
                                              const float* __restrict__ bias,
                                              float* __restrict__ out) {
    constexpr int NOUT = WIN - 1;
    constexpr int OCT = 32;
    constexpr int KT = 32;
    constexpr int MAXU = (NOUT + 15) / 16;
    constexpr int PSTRIDE = (WIN % 2) ? (WIN + 1) : WIN;
    constexpr int WSTRIDE = 2 * KT + 2;

    __shared__ __align__(16) float pt[KT * PSTRIDE];
    __shared__ __align__(16) float wt[OCT * WSTRIDE];

    const int n = blockIdx.x;
    const int ocBase = blockIdx.y * OCT;
    const int tx = threadIdx.x;
    const int ocg = tx >> 4;
    const int ol = tx & 15;
    const int oc0 = ocBase + 2 * ocg;
    const int oc1 = oc0 + 1;

    float acc[2][MAXU];
    #pragma unroll
    for (int a = 0; a < 2; ++a)
        #pragma unroll
        for (int r = 0; r < MAXU; ++r) acc[a][r] = 0.f;

    const float* inn = in + (size_t)n * IC * WIN;

    for (int icb = 0; icb < IC; icb += KT) {
        const int kt = min(KT, IC - icb);
        __syncthreads();
        for (int i = tx; i < KT * WIN; i += 256) {
            const int r = i / WIN, c = i - r * WIN;
            pt[r * PSTRIDE + c] = (r < kt) ? inn[icb * WIN + i] : 0.0f;
        }
        for (int i = tx; i < OCT * 2 * KT; i += 256) {
            const int r = i / (2 * KT), c = i - r * (2 * KT);
            const int oc = ocBase + r;
            const int ic = icb + (c >> 1);
            float v = 0.f;
            if (oc < OC && ic < IC) v = w[((size_t)oc * IC + ic) * 2 + (c & 1)];
            wt[r * WSTRIDE + c] = v;
        }
        __syncthreads();
        #pragma unroll 4
        for (int ic = 0; ic < KT; ++ic) {
            const float2 w0 = *(const float2*)&wt[(2 * ocg) * WSTRIDE + 2 * ic];
            const float2 w1v = *(const float2*)&wt[(2 * ocg + 1) * WSTRIDE + 2 * ic];
            #pragma unroll
            for (int r = 0; r < MAXU; ++r) {
                const int u = ol + 16 * r;
                if (u < NOUT) {
                    const float p0 = pt[ic * PSTRIDE + u];
                    const float p1v = pt[ic * PSTRIDE + u + 1];
                    acc[0][r] += w0.x * p0 + w0.y * p1v;
                    acc[1][r] += w1v.x * p0 + w1v.y * p1v;
                }
            }
        }
    }

    const float b0 = (oc0 < OC) ? bias[oc0] : 0.f;
    const float b1v = (oc1 < OC) ? bias[oc1] : 0.f;
    float* outn = out + (size_t)n * OC * NOUT;
    #pragma unroll
    for (int r = 0; r < MAXU; ++r) {
        const int u = ol + 16 * r;
        if (u < NOUT) {
            if (oc0 < OC) outn[oc0 * NOUT + u] = fmaxf(acc[0][r] + b0, 0.f);
            if (oc1 < OC) outn[oc1 * NOUT + u] = fmaxf(acc[1][r] + b1v, 0.f);
        }
    }
}

// ---------------------------------------------------------------------------
// fc_cnn: seq[n][o] = z4[n][2300] . W[o] + b[o]   (one wave per output)
__global__ void k_fc_cnn(const float* __restrict__ z4, const float* __restrict__ w,
                         const float* __restrict__ b, float* __restrict__ seq) {
    const int n = blockIdx.x;
    const int wid = threadIdx.x >> 6, lane = threadIdx.x & 63;
    const int o = blockIdx.y * 4 + wid;                    // < 100
    const float4* zr = (const float4*)(z4 + (size_t)n * 2300);
    const float4* wr = (const float4*)(w + (size_t)o * 2300);
    float acc = 0.f;
    for (int m = lane; m < 575; m += 64) {
        const float4 wv = wr[m];
        const float4 zv = zr[m];
        acc += wv.x * zv.x + wv.y * zv.y + wv.z * zv.z + wv.w * zv.w;
    }
    #pragma unroll
    for (int off = 32; off > 0; off >>= 1) acc += __shfl_down(acc, off);
    if (lane == 0) seq[n * 100 + o] = acc + b[o];
}

// xg (PERMUTED gate layout p: gate=(p%4), unit=p/4) = seq @ W_ih.T + b_ih + b_hh
__global__ void k_xg(const float* __restrict__ seq, const float* __restrict__ wih,
                     const float* __restrict__ bih, const float* __restrict__ bhh,
                     float* __restrict__ xg) {
    const int n = blockIdx.x;
    __shared__ __align__(16) float s[100];
    if (threadIdx.x < 100) s[threadIdx.x] = seq[n * 100 + threadIdx.x];
    __syncthreads();
    const int p = threadIdx.x;
    if (p < 400) {
        const int go = (p & 3) * 100 + (p >> 2);
        const float4* wr = (const float4*)(wih + (size_t)go * 100);
        const float4* s4 = (const float4*)s;
        float4 a = {0.f, 0.f, 0.f, 0.f};
        #pragma unroll
        for (int m = 0; m < 25; ++m) {
            const float4 wv = wr[m];
            const float4 sv = s4[m];
            a.x += wv.x * sv.x; a.y += wv.y * sv.y;
            a.z += wv.z * sv.z; a.w += wv.w * sv.w;
        }
        xg[n * 400 + p] = bih[go] + bhh[go] + a.x + a.y + a.z + a.w;
    }
}

// LSTM: one block per batch; gate quadruple within a lane-quad -> 1 barrier/step
__global__ __launch_bounds__(512) void k_lstm(const float* __restrict__ xg,
                                              const float* __restrict__ whhT,
                                              const float* __restrict__ fw,
                                              const float* __restrict__ fb,
                                              float* __restrict__ outp) {
    const int bb = blockIdx.x;
    const int tx = threadIdx.x;
    __shared__ __align__(16) float hb[2][104];
    float wreg[100];
    if (tx < 400) {
        #pragma unroll
        for (int m = 0; m < 100; ++m) wreg[m] = whhT[m * 400 + tx];
    }
    float creg = 0.f;
    if (tx < 104) { hb[0][tx] = 0.f; hb[1][tx] = 0.f; }
    float xnext = (tx < 400) ? xg[(size_t)(bb * T_) * 400 + tx] : 0.f;
    __syncthreads();
    const int lane = tx & 63, base = lane & ~3;
    for (int t = 0; t < T_; ++t) {
        float acc = 0.f;
        if (tx < 400) {
            acc = xnext;
            if (t + 1 < T_) xnext = xg[(size_t)(bb * T_ + t + 1) * 400 + tx];
            const float4* h4 = (const float4*)&hb[t & 1][0];
            #pragma unroll
            for (int m4 = 0; m4 < 25; ++m4) {
                const float4 hv = h4[m4];
                acc += hv.x * wreg[4 * m4 + 0] + hv.y * wreg[4 * m4 + 1]
                     + hv.z * wreg[4 * m4 + 2] + hv.w * wreg[4 * m4 + 3];
            }
        }
        const float gI = __shfl(acc, base + 0);
        const float gF = __shfl(acc, base + 1);
        const float gG = __shfl(acc, base + 2);
        const float gO = __shfl(acc, base + 3);
        if (tx < 400) {
            const float cn = sigm(gF) * creg + sigm(gI) * tanhf(gG);
            creg = cn;
            if ((tx & 3) == 0) hb[(t + 1) & 1][tx >> 2] = sigm(gO) * tanhf(cn);
        }
        __syncthreads();
    }
    if (tx < 2) {
        float acc = fb[tx];
        for (int j = 0; j < 100; ++j) acc += hb[0][j] * fw[tx * 100 + j];
        outp[bb * 2 + tx] = acc;
    }
}

// ---------------------------------------------------------------------------
extern "C" void kernel_launch(void* const* d_in, const int* in_sizes, int n_in,
                              void* d_out, int out_size, void* d_ws, size_t ws_size,
                              hipStream_t stream) {
    (void)in_sizes; (void)n_in; (void)out_size; (void)ws_size;
    const float* replay = (const float*)d_in[0];
    const float* emb    = (const float*)d_in[1];
    const float* ccw    = (const float*)d_in[2];
    const float* ccb    = (const float*)d_in[3];
    const float* fcw    = (const float*)d_in[4];
    const float* fcb    = (const float*)d_in[5];
    const float* w1     = (const float*)d_in[6];
    const float* b1     = (const float*)d_in[7];
    const float* w2     = (const float*)d_in[8];
    const float* b2     = (const float*)d_in[9];
    const float* w3     = (const float*)d_in[10];
    const float* b3     = (const float*)d_in[11];
    const float* w4     = (const float*)d_in[12];
    const float* b4     = (const float*)d_in[13];
    const float* fcnw   = (const float*)d_in[14];
    const float* fcnb   = (const float*)d_in[15];
    const float* wih    = (const float*)d_in[16];
    const float* whh    = (const float*)d_in[17];
    const float* bih    = (const float*)d_in[18];
    const float* bhh    = (const float*)d_in[19];
    const float* fow    = (const float*)d_in[20];
    const float* fob    = (const float*)d_in[21];

    float* ws = (float*)d_ws;
    float*  sca  = ws + 0;                      // 12800
    float*  wsum = ws + 12800;                  // 2048
    float*  sa   = ws + 14848;                  // 123392 -> 138240
    float*  seq  = ws + 138240;                 // 6400
    float*  xg   = ws + 144640;                 // 25600
    float*  whhT = ws + 170240;                 // 40000 -> 210240
    float*  yb   = ws + 210240;                 // 61504 -> pad 272384
    float*  p3   = ws + 272384;                 // 370176 -> 642560
    float*  z4   = ws + 642560;                 // 147200 -> 789760
    ushort* A2   = (ushort*)(ws + 789760);      // 2*512*1024 sh = 524288 fl
    ushort* A3   = (ushort*)(ws + 1314048);     // 2*256*512 sh = 131072 fl
    ushort* Bt2  = (ushort*)(ws + 1445120);     // 6401*1024 sh = 3277312 fl
    ushort* Bt3  = (ushort*)(ws + 4722432);     // 3201*512 sh = 819456 fl
    ushort* p2b  = (ushort*)(ws + 5541888);     // 64*482*49 sh = 755776 fl (end 6297664)
    float*  outp = (float*)d_out;

    k_sca_conv<<<dim3(64, 4), 256, 0, stream>>>(replay, ccw, ccb, yb);
    k_sca_fc<<<dim3(64, 50), 256, 0, stream>>>(yb, fcw, fcb, sca);
    k_wsum<<<964, 64, 0, stream>>>(w1, wsum);
    k_sa<<<dim3(4, 64), 256, 0, stream>>>(replay, w1, sa);
    k_prep_w<<<5277, 256, 0, stream>>>(w2, w3, whh, A2, A3, whhT);
    k_cnn1<16><<<dim3(64, 64), 256, 0, stream>>>(sca, emb, w1, b1, wsum, sa, Bt2);
    // gemm1: M=512(482), K=1024(964), B rows 64*100; out -> p2b bf16 [n][482][49]
    k_gemm_conv<482, 100, 98, 1024, 512, true, 8, 100>
        <<<800, 256, 0, stream>>>(A2, Bt2, b2, p2b);
    k_tr3<<<64, 256, 0, stream>>>(p2b, Bt3);
    // gemm2: M=256(241), K=512(482), B rows 64*50; out -> p3 fp32 [n][241][24]
    k_gemm_conv<241, 50, 48, 512, 256, false, 4, 50>
        <<<200, 256, 0, stream>>>(A3, Bt3, b3, p3);
    k_conv<241, 100, 24><<<dim3(64, 4), 256, 0, stream>>>(p3, w4, b4, z4);
    k_fc_cnn<<<dim3(64, 25), 256, 0, stream>>>(z4, fcnw, fcnb, seq);
    k_xg<<<64, 512, 0, stream>>>(seq, wih, bih, bhh, xg);
    k_lstm<<<2, 512, 0, stream>>>(xg, whhT, fow, fob, outp);
}